// Round 11
// baseline (46.042 us; speedup 1.0000x reference)
//
#include <hip/hip_runtime.h>

#define WT_L0 8192
#define WT_NT 256

typedef float f4 __attribute__((ext_vector_type(4)));
typedef float f2 __attribute__((ext_vector_type(2)));

// Half-row blocks, 3 phases / 2 barriers. Only sig1 & sig2 live in LDS;
// down1/down2 are recomputed in registers at their consumers.
// LDS floats (12.4 KB):
//   sig1 f2 cells [0,1036)  cell j <-> x f4/pair index P = 1024h-6+j (0 if OOB)
//   sig2 [2072,3108)        ls     <-> global s = 1024h-6+ls
__global__ __launch_bounds__(WT_NT) void wavelet1d_kernel(
    const float* __restrict__ x,
    const float* __restrict__ w0,
    const float* __restrict__ w1,
    const float* __restrict__ w2,
    float* __restrict__ out)
{
    __shared__ float buf[3108];
    const int blk = blockIdx.x;
    const int row = blk >> 1;
    const int h   = blk & 1;
    const int t   = threadIdx.x;
    const float* __restrict__ xr = x + (size_t)row * WT_L0;
    float* __restrict__ outr = out + (size_t)row * 3 * WT_L0;

    float f0[3], f1[5], f2a[7];
    #pragma unroll
    for (int k = 0; k < 3; ++k) f0[k] = w0[k];
    #pragma unroll
    for (int k = 0; k < 5; ++k) f1[k] = w1[k];
    #pragma unroll
    for (int k = 0; k < 7; ++k) f2a[k] = w2[k];

    // composed pool∘conv5 (stride-2, 6 taps) and pool∘conv7 (stride-2, 8 taps)
    const float g0 = 0.5f*f1[0], g1 = 0.5f*(f1[0]+f1[1]), g2 = 0.5f*(f1[1]+f1[2]),
                g3 = 0.5f*(f1[2]+f1[3]), g4 = 0.5f*(f1[3]+f1[4]), g5 = 0.5f*f1[4];
    const float h0 = 0.5f*f2a[0], h1 = 0.5f*(f2a[0]+f2a[1]), h2 = 0.5f*(f2a[1]+f2a[2]),
                h3 = 0.5f*(f2a[2]+f2a[3]), h4 = 0.5f*(f2a[3]+f2a[4]),
                h5 = 0.5f*(f2a[4]+f2a[5]), h6 = 0.5f*(f2a[5]+f2a[6]), h7 = 0.5f*f2a[6];

    f2*    sig1_2 = (f2*)buf;          // cells [0,1036)
    float* sig2   = buf + 2072;        // [0,1036)

    // ---- P1: stage sig1 (halo, OOB=0) + conv3 -> out0 on own span ----
    {
        const f4* __restrict__ xr4 = (const f4*)xr;
        f4* __restrict__ out0_4 = (f4*)outr;
        const int Gbase = 1024 * h - 6;
        for (int j = t; j < 1036; j += WT_NT) {
            const int G = Gbase + j;                 // global x f4 index
            f4 v = (G >= 0 && G < 2048) ? xr4[G] : (f4)(0.f);
            f2 s; s.x = 0.5f * (v.x + v.y); s.y = 0.5f * (v.z + v.w);
            sig1_2[j] = s;
            if (j >= 6 && j < 1030) {                // own span: G in [1024h, 1024h+1024)
                float lm = (G > 0)    ? xr[4 * G - 1] : 0.f;
                float rp = (G < 2047) ? xr[4 * G + 4] : 0.f;
                f4 o;
                o.x = f0[0]*lm  + f0[1]*v.x + f0[2]*v.y;
                o.y = f0[0]*v.x + f0[1]*v.y + f0[2]*v.z;
                o.z = f0[0]*v.y + f0[1]*v.z + f0[2]*v.w;
                o.w = f0[0]*v.z + f0[1]*v.w + f0[2]*rp;
                out0_4[G] = o;
            }
        }
    }
    __syncthreads();

    // ---- P2: out1 via register-down1; stage sig2 = pool(sig1) ----
    {
        f4* __restrict__ out1_4 = (f4*)(outr + WT_L0);
        #pragma unroll
        for (int c = 0; c < 4; ++c) {
            int lq = t + WT_NT * c;                  // 0..1023
            int q  = 1024 * h + lq;                  // global down1 / out1-f4 index
            // down1[m] = sum_i g_i * sig1[2m-2+i] -> pairs m-1,m,m+1
            // local cell for pair P: P - (1024h-6) ; need pairs q-2..q+2 -> cells lq+4..lq+8
            f2 a0 = sig1_2[lq + 4], a1 = sig1_2[lq + 5], a2 = sig1_2[lq + 6],
               a3 = sig1_2[lq + 7], a4 = sig1_2[lq + 8];
            float dmv = g0*a0.x + g1*a0.y + g2*a1.x + g3*a1.y + g4*a2.x + g5*a2.y;
            float d0v = g0*a1.x + g1*a1.y + g2*a2.x + g3*a2.y + g4*a3.x + g5*a3.y;
            float dpv = g0*a2.x + g1*a2.y + g2*a3.x + g3*a3.y + g4*a4.x + g5*a4.y;
            float dm = (q > 0)    ? dmv : d0v;       // interp edge-replicate
            float dp = (q < 2047) ? dpv : d0v;
            f4 o;
            o.x = 0.375f  * dm + 0.625f * d0v;
            o.y = 0.1875f * dm + 0.75f  * d0v + 0.0625f * dp;
            o.z = 0.0625f * dm + 0.75f  * d0v + 0.1875f * dp;
            o.w = 0.625f  * d0v + 0.375f * dp;
            out1_4[q] = o;
        }
        for (int ls = t; ls < 1036; ls += WT_NT) {
            f2 p = sig1_2[ls];
            sig2[ls] = 0.5f * (p.x + p.y);
        }
    }
    __syncthreads();

    // ---- P3: out2 via register-down2 ----
    {
        f4* __restrict__ out2_4 = (f4*)(outr + 2 * WT_L0);
        const int p = t & 1;                         // parity of q (strides even)
        f4 wa, wb, wc;
        if (p == 0) {
            wa = (f4){0.4375f,  0.3125f,  0.21875f, 0.15625f};
            wb = (f4){0.5625f,  0.6875f,  0.75f,    0.75f   };
            wc = (f4){0.f,      0.f,      0.03125f, 0.09375f};
        } else {
            wa = (f4){0.09375f, 0.03125f, 0.f,      0.f     };
            wb = (f4){0.75f,    0.75f,    0.6875f,  0.5625f };
            wc = (f4){0.15625f, 0.21875f, 0.3125f,  0.4375f };
        }
        #pragma unroll
        for (int c = 0; c < 4; ++c) {
            int lq = t + WT_NT * c;                  // 0..1023
            int q  = 1024 * h + lq;                  // global out2 f4 index
            int m  = q >> 1;                         // global down2 index
            int lm = lq >> 1;
            // down2[m2] = sum_i h_i * sig2[2*m2-3+i]; local ls = 2*m2+3+i-1024h
            // need m2 = m-1,m,m+1 -> ls in [2lm+1, 2lm+12]
            float sv[12];
            #pragma unroll
            for (int i = 0; i < 12; ++i) sv[i] = sig2[2 * lm + 1 + i];
            float dmv = h0*sv[0] + h1*sv[1] + h2*sv[2] + h3*sv[3]
                      + h4*sv[4] + h5*sv[5] + h6*sv[6] + h7*sv[7];
            float d0v = h0*sv[2] + h1*sv[3] + h2*sv[4] + h3*sv[5]
                      + h4*sv[6] + h5*sv[7] + h6*sv[8] + h7*sv[9];
            float dpv = h0*sv[4] + h1*sv[5] + h2*sv[6] + h3*sv[7]
                      + h4*sv[8] + h5*sv[9] + h6*sv[10] + h7*sv[11];
            float dm = (m > 0)    ? dmv : d0v;
            float dp = (m < 1023) ? dpv : d0v;
            f4 o = wa * dm + wb * d0v + wc * dp;
            out2_4[q] = o;
        }
    }
}

extern "C" void kernel_launch(void* const* d_in, const int* in_sizes, int n_in,
                              void* d_out, int out_size, void* d_ws, size_t ws_size,
                              hipStream_t stream) {
    const float* x  = (const float*)d_in[0];
    const float* w0 = (const float*)d_in[1];
    const float* w1 = (const float*)d_in[2];
    const float* w2 = (const float*)d_in[3];
    float* out = (float*)d_out;

    const int rows = in_sizes[0] / WT_L0;     // B*C = 2048
    wavelet1d_kernel<<<dim3(rows * 2), dim3(WT_NT), 0, stream>>>(x, w0, w1, w2, out);
}

// Round 12
// 45.410 us; speedup vs baseline: 1.0139x; 1.0139x over previous
//
#include <hip/hip_runtime.h>

#define WT_L0 8192
#define WT_NT 256

typedef float f4 __attribute__((ext_vector_type(4)));
typedef float f2 __attribute__((ext_vector_type(2)));

// Half-row blocks, 3 phases / 2 barriers. Only sig1 & sig2 live in LDS;
// down1/down2 are recomputed in registers at their consumers.
// LDS floats (12.4 KB):
//   sig1 f2 cells [0,1036)  cell j <-> x f4/pair index P = 1024h-6+j (0 if OOB)
//   sig2 [2072,3108)        ls     <-> global s = 1024h-6+ls
__global__ __launch_bounds__(WT_NT) void wavelet1d_kernel(
    const float* __restrict__ x,
    const float* __restrict__ w0,
    const float* __restrict__ w1,
    const float* __restrict__ w2,
    float* __restrict__ out)
{
    __shared__ float buf[3108];
    const int blk = blockIdx.x;
    const int row = blk >> 1;
    const int h   = blk & 1;
    const int t   = threadIdx.x;
    const float* __restrict__ xr = x + (size_t)row * WT_L0;
    float* __restrict__ outr = out + (size_t)row * 3 * WT_L0;

    float f0[3], f1[5], f2a[7];
    #pragma unroll
    for (int k = 0; k < 3; ++k) f0[k] = w0[k];
    #pragma unroll
    for (int k = 0; k < 5; ++k) f1[k] = w1[k];
    #pragma unroll
    for (int k = 0; k < 7; ++k) f2a[k] = w2[k];

    // composed pool∘conv5 (stride-2, 6 taps) and pool∘conv7 (stride-2, 8 taps)
    const float g0 = 0.5f*f1[0], g1 = 0.5f*(f1[0]+f1[1]), g2 = 0.5f*(f1[1]+f1[2]),
                g3 = 0.5f*(f1[2]+f1[3]), g4 = 0.5f*(f1[3]+f1[4]), g5 = 0.5f*f1[4];
    const float h0 = 0.5f*f2a[0], h1 = 0.5f*(f2a[0]+f2a[1]), h2 = 0.5f*(f2a[1]+f2a[2]),
                h3 = 0.5f*(f2a[2]+f2a[3]), h4 = 0.5f*(f2a[3]+f2a[4]),
                h5 = 0.5f*(f2a[4]+f2a[5]), h6 = 0.5f*(f2a[5]+f2a[6]), h7 = 0.5f*f2a[6];

    f2*    sig1_2 = (f2*)buf;          // cells [0,1036)
    float* sig2   = buf + 2072;        // [0,1036)

    const int Gbase = 1024 * h - 6;

    // ---- P1a: stage the 12 halo cells (j in {0..5} U {1030..1035}) ----
    if (t < 12) {
        const f4* __restrict__ xr4 = (const f4*)xr;
        int j = (t < 6) ? t : (1024 + t);            // 0..5 or 1030..1035
        int G = Gbase + j;
        f4 v = (G >= 0 && G < 2048) ? xr4[G] : (f4)(0.f);
        f2 s; s.x = 0.5f * (v.x + v.y); s.y = 0.5f * (v.z + v.w);
        sig1_2[j] = s;
    }

    // ---- P1b: main span, exactly 4 unguarded trips: conv3 -> out0, stage sig1 ----
    {
        const f4* __restrict__ xr4 = (const f4*)xr;
        f4* __restrict__ out0_4 = (f4*)outr;
        #pragma unroll
        for (int c = 0; c < 4; ++c) {
            int j = 6 + t + WT_NT * c;               // 6..1029
            int G = Gbase + j;                       // own span: [1024h, 1024h+1024)
            f4 v = xr4[G];
            f2 s; s.x = 0.5f * (v.x + v.y); s.y = 0.5f * (v.z + v.w);
            sig1_2[j] = s;
            float lm = (G > 0)    ? xr[4 * G - 1] : 0.f;
            float rp = (G < 2047) ? xr[4 * G + 4] : 0.f;
            f4 o;
            o.x = f0[0]*lm  + f0[1]*v.x + f0[2]*v.y;
            o.y = f0[0]*v.x + f0[1]*v.y + f0[2]*v.z;
            o.z = f0[0]*v.y + f0[1]*v.z + f0[2]*v.w;
            o.w = f0[0]*v.z + f0[1]*v.w + f0[2]*rp;
            out0_4[G] = o;
        }
    }
    __syncthreads();

    // ---- P2: out1 via register-down1; stage sig2 = pool(sig1) ----
    {
        f4* __restrict__ out1_4 = (f4*)(outr + WT_L0);
        #pragma unroll
        for (int c = 0; c < 4; ++c) {
            int lq = t + WT_NT * c;                  // 0..1023
            int q  = 1024 * h + lq;                  // global down1 / out1-f4 index
            // down1[m] = sum_i g_i * sig1[2m-2+i] -> pairs m-1..m+1; cells lq+4..lq+8
            f2 a0 = sig1_2[lq + 4], a1 = sig1_2[lq + 5], a2 = sig1_2[lq + 6],
               a3 = sig1_2[lq + 7], a4 = sig1_2[lq + 8];
            float dmv = g0*a0.x + g1*a0.y + g2*a1.x + g3*a1.y + g4*a2.x + g5*a2.y;
            float d0v = g0*a1.x + g1*a1.y + g2*a2.x + g3*a2.y + g4*a3.x + g5*a3.y;
            float dpv = g0*a2.x + g1*a2.y + g2*a3.x + g3*a3.y + g4*a4.x + g5*a4.y;
            float dm = (q > 0)    ? dmv : d0v;       // interp edge-replicate
            float dp = (q < 2047) ? dpv : d0v;
            f4 o;
            o.x = 0.375f  * dm + 0.625f * d0v;
            o.y = 0.1875f * dm + 0.75f  * d0v + 0.0625f * dp;
            o.z = 0.0625f * dm + 0.75f  * d0v + 0.1875f * dp;
            o.w = 0.625f  * d0v + 0.375f * dp;
            out1_4[q] = o;
        }
        #pragma unroll
        for (int c = 0; c < 5; ++c) {
            int ls = t + WT_NT * c;
            if (ls < 1036) {
                f2 p = sig1_2[ls];
                sig2[ls] = 0.5f * (p.x + p.y);
            }
        }
    }
    __syncthreads();

    // ---- P3: out2 via register-down2 ----
    {
        f4* __restrict__ out2_4 = (f4*)(outr + 2 * WT_L0);
        const int p = t & 1;                         // parity of q (strides even)
        f4 wa, wb, wc;
        if (p == 0) {
            wa = (f4){0.4375f,  0.3125f,  0.21875f, 0.15625f};
            wb = (f4){0.5625f,  0.6875f,  0.75f,    0.75f   };
            wc = (f4){0.f,      0.f,      0.03125f, 0.09375f};
        } else {
            wa = (f4){0.09375f, 0.03125f, 0.f,      0.f     };
            wb = (f4){0.75f,    0.75f,    0.6875f,  0.5625f };
            wc = (f4){0.15625f, 0.21875f, 0.3125f,  0.4375f };
        }
        #pragma unroll
        for (int c = 0; c < 4; ++c) {
            int lq = t + WT_NT * c;                  // 0..1023
            int q  = 1024 * h + lq;                  // global out2 f4 index
            int m  = q >> 1;                         // global down2 index
            int lm = lq >> 1;
            // down2[m2] = sum_i h_i * sig2[2*m2-3+i]; need ls in [2lm+1, 2lm+12]
            float sv[12];
            #pragma unroll
            for (int i = 0; i < 12; ++i) sv[i] = sig2[2 * lm + 1 + i];
            float dmv = h0*sv[0] + h1*sv[1] + h2*sv[2] + h3*sv[3]
                      + h4*sv[4] + h5*sv[5] + h6*sv[6] + h7*sv[7];
            float d0v = h0*sv[2] + h1*sv[3] + h2*sv[4] + h3*sv[5]
                      + h4*sv[6] + h5*sv[7] + h6*sv[8] + h7*sv[9];
            float dpv = h0*sv[4] + h1*sv[5] + h2*sv[6] + h3*sv[7]
                      + h4*sv[8] + h5*sv[9] + h6*sv[10] + h7*sv[11];
            float dm = (m > 0)    ? dmv : d0v;
            float dp = (m < 1023) ? dpv : d0v;
            f4 o = wa * dm + wb * d0v + wc * dp;
            out2_4[q] = o;
        }
    }
}

extern "C" void kernel_launch(void* const* d_in, const int* in_sizes, int n_in,
                              void* d_out, int out_size, void* d_ws, size_t ws_size,
                              hipStream_t stream) {
    const float* x  = (const float*)d_in[0];
    const float* w0 = (const float*)d_in[1];
    const float* w1 = (const float*)d_in[2];
    const float* w2 = (const float*)d_in[3];
    float* out = (float*)d_out;

    const int rows = in_sizes[0] / WT_L0;     // B*C = 2048
    wavelet1d_kernel<<<dim3(rows * 2), dim3(WT_NT), 0, stream>>>(x, w0, w1, w2, out);
}